// Round 12
// baseline (412.812 us; speedup 1.0000x reference)
//
#include <hip/hip_runtime.h>
#include <hip/hip_bf16.h>

// Transformer block: B=4, S=2048, D=1024, H=4096, fp32 in/out, bf16 MFMA compute.
//   gemm8p : BM=256,BN=256,BK=32, 4 buffers, counted vmcnt, 1 blk/CU (scores, FFN1)
//   gemm128: BM=128,BN=256,BK=64, 3 buffers, counted vmcnt, 1 blk/CU (PV, Wo, FFN2)
//   gemm256q: BM=256,BN=256,BK=32, 2 buffers, vmcnt(0)/tile, 2 blk/CU (QKV:
//             grid 384, all co-resident at 2/CU, TLP hides the per-tile drain)
// T2 swizzle (pre-swizzled global src, linear LDS dest), T5 setprio, T1 XCD swz.
// All weight transposes merged into one dispatch.

typedef __bf16 bf16_t;
typedef __bf16 bf16x8 __attribute__((ext_vector_type(8)));
typedef float  f32x4  __attribute__((ext_vector_type(4)));

#define EPI_QKV            0
#define EPI_BF16_SCALE     1
#define EPI_BF16           3
#define EPI_F32_BIAS_RES   4
#define EPI_BF16_RELU_BIAS 5

__device__ __forceinline__ void gl_lds16(const bf16_t* g, void* l) {
  __builtin_amdgcn_global_load_lds(
      (const __attribute__((address_space(1))) void*)g,
      (__attribute__((address_space(3))) void*)l, 16, 0, 0);
}

// ---------------- BM=256 x BN=256, BK=32, 4-buffer pipeline ----------------
template<int BM, int EPI>
__global__ __launch_bounds__(512, 2)
void gemm8p(const bf16_t* __restrict__ A, const bf16_t* __restrict__ B,
            float* __restrict__ Cf, bf16_t* __restrict__ Cb,
            const float* __restrict__ bias,
            int M, int N, int K, long sAb, long sBb, long sCb, float scale)
{
  constexpr int BN  = 256;
  constexpr int WTM = BM / 2;
  constexpr int MF  = WTM / 16;
  constexpr int NF  = 4;
  constexpr int LA  = BM / 128;
  constexpr int LB  = 2;
  constexpr int L   = LA + LB;
  constexpr int L0  = 2;
  constexpr int SBUF = (BM + BN) * 64;
  constexpr int W   = 2 * L;
  __shared__ __align__(16) char lds[4 * SBUF];

  const int tid = threadIdx.x;
  const int l   = tid & 63;
  const int w   = tid >> 6;
  const int wm  = w >> 2;
  const int wn  = w & 3;

  const int nx = gridDim.x, ny = gridDim.y;
  const int tot = nx * ny * gridDim.z;
  int id = blockIdx.x + nx * (blockIdx.y + ny * blockIdx.z);
  const int cpx = tot >> 3;
  int s = (id & 7) * cpx + (id >> 3);
  const int bx = s % nx; int rq = s / nx;
  const int by = rq % ny; const int bz = rq / ny;

  const bf16_t* Ab = A + (long)bz * sAb;
  const bf16_t* Bb = B + (long)bz * sBb;
  const int m0 = by * BM, n0 = bx * BN;
  const int NT = K >> 5;

  const int srow = w * 16 + (l >> 2);
  const int scol = ((l & 3) ^ ((l >> 3) & 3)) * 8;
  const bf16_t* srcA[LA]; const bf16_t* srcB[LB];
#pragma unroll
  for (int q = 0; q < LA; ++q) srcA[q] = Ab + (long)(m0 + q * 128 + srow) * K + scol;
#pragma unroll
  for (int q = 0; q < LB; ++q) srcB[q] = Bb + (long)(n0 + q * 128 + srow) * K + scol;
  const int ldsA = w * 1024;
  const int ldsB = BM * 64 + w * 1024;

  const int rA0 = wm * WTM + (l & 15);
  const int rB0 = wn * 64 + (l & 15);
  const int xoff = 16 * ((l >> 4) ^ ((l >> 1) & 3));

  f32x4 acc[MF][NF] = {};
  bf16x8 afr[MF / 2], bfr[NF];

#pragma unroll
  for (int d = 0; d < 3; ++d) {
    char* bufS = lds + d * SBUF;
    const long kst = (long)d * 32;
#pragma unroll
    for (int q = 0; q < LA; ++q) gl_lds16(srcA[q] + kst, bufS + ldsA + q * 8192);
#pragma unroll
    for (int q = 0; q < LB; ++q) gl_lds16(srcB[q] + kst, bufS + ldsB + q * 8192);
  }
  asm volatile("s_waitcnt vmcnt(%0)" :: "n"(W) : "memory");
  __builtin_amdgcn_s_barrier();
  __builtin_amdgcn_sched_barrier(0);

  for (int t = 0; t < NT; ++t) {
    const char* bufR = lds + (t & 3) * SBUF;
    char* bufS = lds + ((t + 3) & 3) * SBUF;
    const int tst = t + 3;
    const long kst = (long)((tst < NT) ? tst : (NT - 1)) * 32;

    // phase 0: B[all] + A[half0]
#pragma unroll
    for (int nf = 0; nf < NF; ++nf)
      bfr[nf] = *(const bf16x8*)(bufR + BM * 64 + (rB0 + nf * 16) * 64 + xoff);
#pragma unroll
    for (int mf = 0; mf < MF / 2; ++mf)
      afr[mf] = *(const bf16x8*)(bufR + (rA0 + mf * 16) * 64 + xoff);
#pragma unroll
    for (int q = 0; q < L0; ++q) {
      if (q < LA) gl_lds16(srcA[q] + kst, bufS + ldsA + q * 8192);
      else        gl_lds16(srcB[q - LA] + kst, bufS + ldsB + (q - LA) * 8192);
    }
    __builtin_amdgcn_s_barrier();
    __builtin_amdgcn_s_setprio(1);
#pragma unroll
    for (int mf = 0; mf < MF / 2; ++mf)
#pragma unroll
      for (int nf = 0; nf < NF; ++nf)
        acc[mf][nf] = __builtin_amdgcn_mfma_f32_16x16x32_bf16(afr[mf], bfr[nf], acc[mf][nf], 0, 0, 0);
    __builtin_amdgcn_s_setprio(0);
    __builtin_amdgcn_s_barrier();

    // phase 1: A[half1]
#pragma unroll
    for (int mf = 0; mf < MF / 2; ++mf)
      afr[mf] = *(const bf16x8*)(bufR + (rA0 + (MF / 2 + mf) * 16) * 64 + xoff);
#pragma unroll
    for (int q = L0; q < L; ++q) {
      if (q < LA) gl_lds16(srcA[q] + kst, bufS + ldsA + q * 8192);
      else        gl_lds16(srcB[q - LA] + kst, bufS + ldsB + (q - LA) * 8192);
    }
    __builtin_amdgcn_s_barrier();
    __builtin_amdgcn_s_setprio(1);
#pragma unroll
    for (int mf = 0; mf < MF / 2; ++mf)
#pragma unroll
      for (int nf = 0; nf < NF; ++nf)
        acc[MF / 2 + mf][nf] = __builtin_amdgcn_mfma_f32_16x16x32_bf16(afr[mf], bfr[nf], acc[MF / 2 + mf][nf], 0, 0, 0);
    __builtin_amdgcn_s_setprio(0);
    asm volatile("s_waitcnt vmcnt(%0)" :: "n"(W) : "memory");
    __builtin_amdgcn_s_barrier();
    __builtin_amdgcn_sched_barrier(0);
  }
  asm volatile("s_waitcnt vmcnt(0)" ::: "memory");

  const int colB0 = n0 + wn * 64 + (l & 15);
  const int rowB0 = m0 + wm * WTM + ((l >> 4) << 2);
#pragma unroll
  for (int mi = 0; mi < MF; ++mi) {
#pragma unroll
    for (int ni = 0; ni < NF; ++ni) {
      const int col = colB0 + ni * 16;
#pragma unroll
      for (int j = 0; j < 4; ++j) {
        const int row = rowB0 + mi * 16 + j;
        const float v = acc[mi][ni][j];
        if constexpr (EPI == EPI_BF16_SCALE) {
          Cb[sCb * bz + (long)row * N + col] = (bf16_t)(v * scale);
        } else { // EPI_BF16_RELU_BIAS
          const float u = v + bias[col];
          Cb[(long)row * N + col] = (bf16_t)(u > 0.f ? u : 0.f);
        }
      }
    }
  }
}

// ---------------- BM=128 x BN=256, BK=64, 3-buffer pipeline ----------------
template<int EPI>
__global__ __launch_bounds__(512, 1)
void gemm128(const bf16_t* __restrict__ A, const bf16_t* __restrict__ B,
             float* __restrict__ Cf, bf16_t* __restrict__ Cb,
             const float* __restrict__ bias, const float* __restrict__ resid,
             int M, int N, int K, long sAb, long sBb, long sCb)
{
  constexpr int SBUF = 49152;
  __shared__ __align__(16) char lds[3 * SBUF];
  const int tid = threadIdx.x;
  const int l   = tid & 63;
  const int w   = tid >> 6;
  const int wm  = w >> 2, wn = w & 3;

  const int nx = gridDim.x, ny = gridDim.y;
  const int tot = nx * ny * gridDim.z;
  int id = blockIdx.x + nx * (blockIdx.y + ny * blockIdx.z);
  const int cpx = tot >> 3;
  int sid = (id & 7) * cpx + (id >> 3);
  const int bx = sid % nx; int rq = sid / nx;
  const int by = rq % ny; const int bz = rq / ny;

  const bf16_t* Ab = A + (long)bz * sAb;
  const bf16_t* Bb = B + (long)bz * sBb;
  const int m0 = by * 128, n0 = bx * 256;
  const int NT = K >> 6;

  const int scol = ((l & 7) ^ (l >> 3)) * 8;
  const bf16_t* srcA = Ab + (long)(m0 + 16 * w + (l >> 3)) * K + scol;
  const bf16_t* srcB = Bb + (long)(n0 + 32 * w + (l >> 3)) * K + scol;
  const int dA = w * 2048 + l * 16;
  const int dB = 16384 + w * 4096 + l * 16;

  const int rA = wm * 64 + (l & 15);
  const int rB = wn * 64 + (l & 15);
  const int xo = ((l >> 4) ^ (l & 7)) * 16;
  const int aoff = rA * 128 + xo;
  const int boff = 16384 + rB * 128 + xo;

  f32x4 acc[4][4] = {};
  bf16x8 af[4], bv[4];

  {
    char* b0 = lds; char* b1 = lds + SBUF;
#pragma unroll
    for (int q = 0; q < 2; ++q) gl_lds16(srcA + (long)q * 8 * K, b0 + dA + q * 1024);
#pragma unroll
    for (int q = 0; q < 4; ++q) gl_lds16(srcB + (long)q * 8 * K, b0 + dB + q * 1024);
#pragma unroll
    for (int q = 0; q < 2; ++q) gl_lds16(srcA + (long)q * 8 * K + 64, b1 + dA + q * 1024);
#pragma unroll
    for (int q = 0; q < 4; ++q) gl_lds16(srcB + (long)q * 8 * K + 64, b1 + dB + q * 1024);
  }
  asm volatile("s_waitcnt vmcnt(6)" ::: "memory");
  __builtin_amdgcn_s_barrier();
  __builtin_amdgcn_sched_barrier(0);

  int ir = 0, is = 2;
  for (int t = 0; t < NT; ++t) {
    const char* bufR = lds + ir * SBUF;
    char* bufS = lds + is * SBUF;
    const int tst = (t + 2 < NT) ? t + 2 : NT - 1;
    const long kst = (long)tst * 64;

#pragma unroll
    for (int nf = 0; nf < 4; ++nf) bv[nf] = *(const bf16x8*)(bufR + boff + nf * 2048);
#pragma unroll
    for (int mf = 0; mf < 4; ++mf) af[mf] = *(const bf16x8*)(bufR + aoff + mf * 2048);
    gl_lds16(srcA + kst,                 bufS + dA);
    gl_lds16(srcA + (long)8 * K + kst,   bufS + dA + 1024);
    gl_lds16(srcB + kst,                 bufS + dB);
    __builtin_amdgcn_s_barrier();
    __builtin_amdgcn_s_setprio(1);
#pragma unroll
    for (int mf = 0; mf < 4; ++mf)
#pragma unroll
      for (int nf = 0; nf < 4; ++nf)
        acc[mf][nf] = __builtin_amdgcn_mfma_f32_16x16x32_bf16(af[mf], bv[nf], acc[mf][nf], 0, 0, 0);
    __builtin_amdgcn_s_setprio(0);
    __builtin_amdgcn_s_barrier();

#pragma unroll
    for (int nf = 0; nf < 4; ++nf) bv[nf] = *(const bf16x8*)(bufR + ((boff + nf * 2048) ^ 64));
#pragma unroll
    for (int mf = 0; mf < 4; ++mf) af[mf] = *(const bf16x8*)(bufR + ((aoff + mf * 2048) ^ 64));
    gl_lds16(srcB + (long)8 * K + kst,   bufS + dB + 1024);
    gl_lds16(srcB + (long)16 * K + kst,  bufS + dB + 2048);
    gl_lds16(srcB + (long)24 * K + kst,  bufS + dB + 3072);
    __builtin_amdgcn_s_barrier();
    __builtin_amdgcn_s_setprio(1);
#pragma unroll
    for (int mf = 0; mf < 4; ++mf)
#pragma unroll
      for (int nf = 0; nf < 4; ++nf)
        acc[mf][nf] = __builtin_amdgcn_mfma_f32_16x16x32_bf16(af[mf], bv[nf], acc[mf][nf], 0, 0, 0);
    __builtin_amdgcn_s_setprio(0);
    asm volatile("s_waitcnt vmcnt(6)" ::: "memory");
    __builtin_amdgcn_s_barrier();
    __builtin_amdgcn_sched_barrier(0);
    ir = (ir == 2) ? 0 : ir + 1;
    is = (is == 2) ? 0 : is + 1;
  }
  asm volatile("s_waitcnt vmcnt(0)" ::: "memory");

  const int colB0 = n0 + wn * 64 + (l & 15);
  const int rowB0 = m0 + wm * 64 + ((l >> 4) << 2);
#pragma unroll
  for (int mi = 0; mi < 4; ++mi) {
#pragma unroll
    for (int ni = 0; ni < 4; ++ni) {
      const int col = colB0 + ni * 16;
#pragma unroll
      for (int j = 0; j < 4; ++j) {
        const int row = rowB0 + mi * 16 + j;
        const float v = acc[mi][ni][j];
        if constexpr (EPI == EPI_BF16) {
          Cb[sCb * bz + (long)row * N + col] = (bf16_t)v;
        } else { // EPI_F32_BIAS_RES
          Cf[(long)row * N + col] = v + bias[col] + resid[(long)row * N + col];
        }
      }
    }
  }
}

// -- BM=256 x BN=256, BK=32, 2-buffer, vmcnt(0)/tile, 2 blocks/CU (QKV) --
__global__ __launch_bounds__(512, 2)
void gemm256q(const bf16_t* __restrict__ A, const bf16_t* __restrict__ B,
              bf16_t* __restrict__ Cb, bf16_t* __restrict__ Cb2,
              bf16_t* __restrict__ Cb3,
              const float* __restrict__ bias, const float* __restrict__ bias2,
              const float* __restrict__ bias3, int M, int N, int K)
{
  constexpr int SBUF = 32768;   // A 256x32 (16KB) + B 256x32 (16KB)
  __shared__ __align__(16) char lds[2 * SBUF];
  const int tid = threadIdx.x;
  const int l   = tid & 63;
  const int w   = tid >> 6;
  const int wm  = w >> 2, wn = w & 3;

  const int nx = gridDim.x, ny = gridDim.y;
  const int tot = nx * ny;
  int id = blockIdx.x + nx * blockIdx.y;
  const int cpx = tot >> 3;
  int sid = (id & 7) * cpx + (id >> 3);
  const int bx = sid % nx;
  const int by = sid / nx;

  const int m0 = by * 256, n0 = bx * 256;
  const int NT = K >> 5;

  // staging: same pattern as gemm8p (1KB chunk = 16 rows x 64B, pre-swizzled)
  const int srow = w * 16 + (l >> 2);
  const int scol = ((l & 3) ^ ((l >> 3) & 3)) * 8;
  const bf16_t* srcA0 = A + (long)(m0 + srow) * K + scol;
  const bf16_t* srcA1 = A + (long)(m0 + 128 + srow) * K + scol;
  const bf16_t* srcB0 = B + (long)(n0 + srow) * K + scol;
  const bf16_t* srcB1 = B + (long)(n0 + 128 + srow) * K + scol;
  const int ldsA = w * 1024;
  const int ldsB = 16384 + w * 1024;

  const int rA0 = wm * 128 + (l & 15);
  const int rB0 = wn * 64 + (l & 15);
  const int xoff = 16 * ((l >> 4) ^ ((l >> 1) & 3));

  f32x4 acc[8][4] = {};
  bf16x8 afr[4], bfr[4];

  // prologue: stage tile 0 (4 loads/wave)
  gl_lds16(srcA0, lds + ldsA);
  gl_lds16(srcA1, lds + ldsA + 8192);
  gl_lds16(srcB0, lds + ldsB);
  gl_lds16(srcB1, lds + ldsB + 8192);
  asm volatile("s_waitcnt vmcnt(0)" ::: "memory");
  __builtin_amdgcn_s_barrier();
  __builtin_amdgcn_sched_barrier(0);

  for (int t = 0; t < NT; ++t) {
    const char* bufR = lds + (t & 1) * SBUF;
    char* bufS = lds + ((t + 1) & 1) * SBUF;
    const long kst = (long)((t + 1 < NT) ? t + 1 : NT - 1) * 32;

    // phase 0: B[all] + A[half0]; stage A of t+1
#pragma unroll
    for (int nf = 0; nf < 4; ++nf)
      bfr[nf] = *(const bf16x8*)(bufR + 16384 + (rB0 + nf * 16) * 64 + xoff);
#pragma unroll
    for (int mf = 0; mf < 4; ++mf)
      afr[mf] = *(const bf16x8*)(bufR + (rA0 + mf * 16) * 64 + xoff);
    gl_lds16(srcA0 + kst, bufS + ldsA);
    gl_lds16(srcA1 + kst, bufS + ldsA + 8192);
    __builtin_amdgcn_s_barrier();
    __builtin_amdgcn_s_setprio(1);
#pragma unroll
    for (int mf = 0; mf < 4; ++mf)
#pragma unroll
      for (int nf = 0; nf < 4; ++nf)
        acc[mf][nf] = __builtin_amdgcn_mfma_f32_16x16x32_bf16(afr[mf], bfr[nf], acc[mf][nf], 0, 0, 0);
    __builtin_amdgcn_s_setprio(0);
    __builtin_amdgcn_s_barrier();

    // phase 1: A[half1]; stage B of t+1
#pragma unroll
    for (int mf = 0; mf < 4; ++mf)
      afr[mf] = *(const bf16x8*)(bufR + (rA0 + (4 + mf) * 16) * 64 + xoff);
    gl_lds16(srcB0 + kst, bufS + ldsB);
    gl_lds16(srcB1 + kst, bufS + ldsB + 8192);
    __builtin_amdgcn_s_barrier();
    __builtin_amdgcn_s_setprio(1);
#pragma unroll
    for (int mf = 0; mf < 4; ++mf)
#pragma unroll
      for (int nf = 0; nf < 4; ++nf)
        acc[4 + mf][nf] = __builtin_amdgcn_mfma_f32_16x16x32_bf16(afr[mf], bfr[nf], acc[4 + mf][nf], 0, 0, 0);
    __builtin_amdgcn_s_setprio(0);
    asm volatile("s_waitcnt vmcnt(0)" ::: "memory");
    __builtin_amdgcn_s_barrier();
    __builtin_amdgcn_sched_barrier(0);
  }

  const int colB0 = n0 + wn * 64 + (l & 15);
  const int rowB0 = m0 + wm * 128 + ((l >> 4) << 2);
#pragma unroll
  for (int mi = 0; mi < 8; ++mi) {
#pragma unroll
    for (int ni = 0; ni < 4; ++ni) {
      const int col = colB0 + ni * 16;
#pragma unroll
      for (int j = 0; j < 4; ++j) {
        const int row = rowB0 + mi * 16 + j;
        const float v = acc[mi][ni][j];
        if (col < 1024)      Cb [(long)row * 1024 + col]        = (bf16_t)(v + bias[col]);
        else if (col < 2048) Cb2[(long)row * 1024 + col - 1024] = (bf16_t)(v + bias2[col - 1024]);
        else                 Cb3[(long)row * 1024 + col - 2048] = (bf16_t)(v + bias3[col - 2048]);
      }
    }
  }
}

// bf16 transpose: V [4][2048][1024] -> VT [4][1024][2048]. 64x64 tiles.
__global__ __launch_bounds__(256)
void transpose_bf(const bf16_t* __restrict__ V, bf16_t* __restrict__ VT)
{
  __shared__ __align__(16) bf16_t t[64][72];
  const int b = blockIdx.z;
  const int t0 = blockIdx.y * 64, d0 = blockIdx.x * 64;
  const int r = threadIdx.x >> 3;
  const int c = (threadIdx.x & 7) * 8;
  const bf16_t* src = V + ((long)b * 2048 + t0) * 1024 + d0;
#pragma unroll
  for (int h = 0; h < 2; ++h)
    *(bf16x8*)&t[r + 32 * h][c] = *(const bf16x8*)(src + (long)(r + 32 * h) * 1024 + c);
  __syncthreads();
  bf16_t* dst = VT + ((long)b * 1024 + d0) * 2048 + t0;
#pragma unroll
  for (int h = 0; h < 2; ++h) {
    const int d = r + 32 * h;
    bf16x8 o;
#pragma unroll
    for (int j = 0; j < 8; ++j) o[j] = t[c + j][d];
    *(bf16x8*)(dst + (long)d * 2048 + c) = o;
  }
}

// All 6 weight transposes in one dispatch. Flat grid 12288 blocks.
__global__ __launch_bounds__(256)
void transpose_all(const float* __restrict__ Wq, const float* __restrict__ Wk,
                   const float* __restrict__ Wv, const float* __restrict__ Wo,
                   const float* __restrict__ W1, const float* __restrict__ W2,
                   bf16_t* __restrict__ WqkvT, bf16_t* __restrict__ WoT,
                   bf16_t* __restrict__ W1T, bf16_t* __restrict__ W2T)
{
  const int id = blockIdx.x;
  const float* W; bf16_t* WT; int R, C, cb, rb;
  if (id < 4096) {
    const int wsel = id >> 10, loc = id & 1023;
    cb = loc & 31; rb = loc >> 5; R = 1024; C = 1024;
    if (wsel == 0)      { W = Wq; WT = WqkvT; }
    else if (wsel == 1) { W = Wk; WT = WqkvT + 1024L * 1024; }
    else if (wsel == 2) { W = Wv; WT = WqkvT + 2048L * 1024; }
    else                { W = Wo; WT = WoT; }
  } else if (id < 8192) {
    const int loc = id - 4096;
    cb = loc & 127; rb = loc >> 7; R = 1024; C = 4096;
    W = W1; WT = W1T;
  } else {
    const int loc = id - 8192;
    cb = loc & 31; rb = loc >> 5; R = 4096; C = 1024;
    W = W2; WT = W2T;
  }
  __shared__ float t[32][33];
  const int c0 = cb * 32, r0 = rb * 32;
  const int tx = threadIdx.x & 31, ty = threadIdx.x >> 5;
#pragma unroll
  for (int i = 0; i < 32; i += 8)
    t[ty + i][tx] = W[(long)(r0 + ty + i) * C + c0 + tx];
  __syncthreads();
#pragma unroll
  for (int i = 0; i < 32; i += 8)
    WT[(long)(c0 + ty + i) * R + r0 + tx] = (bf16_t)t[tx][ty + i];
}

// LayerNorm over D=1024, one block (256 thr) per row, out = bf16.
__global__ __launch_bounds__(256)
void ln_kernel(const float* __restrict__ x, const float* __restrict__ g,
               const float* __restrict__ be, bf16_t* __restrict__ out)
{
  const long row = blockIdx.x;
  const float4 v = *(const float4*)(x + row * 1024 + threadIdx.x * 4);
  float s  = v.x + v.y + v.z + v.w;
  float s2 = v.x * v.x + v.y * v.y + v.z * v.z + v.w * v.w;
  __shared__ float red[10];
  const int lane = threadIdx.x & 63, w = threadIdx.x >> 6;
#pragma unroll
  for (int off = 32; off; off >>= 1) {
    s  += __shfl_down(s, off);
    s2 += __shfl_down(s2, off);
  }
  if (lane == 0) { red[w] = s; red[4 + w] = s2; }
  __syncthreads();
  if (threadIdx.x == 0) {
    const float ts = red[0] + red[1] + red[2] + red[3];
    const float t2 = red[4] + red[5] + red[6] + red[7];
    const float mu = ts * (1.f / 1024.f);
    const float var = t2 * (1.f / 1024.f) - mu * mu;
    red[8] = mu;
    red[9] = rsqrtf(var + 1e-5f);
  }
  __syncthreads();
  const float mu = red[8], rinv = red[9];
  const int c = threadIdx.x * 4;
  const float4 gv = *(const float4*)(g + c);
  const float4 bvv = *(const float4*)(be + c);
  bf16_t* o = out + row * 1024 + c;
  o[0] = (bf16_t)((v.x - mu) * rinv * gv.x + bvv.x);
  o[1] = (bf16_t)((v.y - mu) * rinv * gv.y + bvv.y);
  o[2] = (bf16_t)((v.z - mu) * rinv * gv.z + bvv.z);
  o[3] = (bf16_t)((v.w - mu) * rinv * gv.w + bvv.w);
}

// Row softmax over S=2048: reads bf16 S from ab, writes fp32 attn to sc and
// bf16 P in-place to ab. One block (256 thr) per row.
__global__ __launch_bounds__(256)
void softmax_kernel(float* __restrict__ sc, bf16_t* __restrict__ ab)
{
  const long row = blockIdx.x;
  const int t0 = threadIdx.x * 8;
  const bf16x8 v8 = *(const bf16x8*)(ab + row * 2048 + t0);
  float e[8];
#pragma unroll
  for (int j = 0; j < 8; ++j) e[j] = (float)v8[j];
  float mx = fmaxf(fmaxf(fmaxf(e[0], e[1]), fmaxf(e[2], e[3])),
                   fmaxf(fmaxf(e[4], e[5]), fmaxf(e[6], e[7])));
  __shared__ float red[4];
  __shared__ float bc[2];
  const int lane = threadIdx.x & 63, w = threadIdx.x >> 6;
#pragma unroll
  for (int off = 32; off; off >>= 1) mx = fmaxf(mx, __shfl_down(mx, off));
  if (lane == 0) red[w] = mx;
  __syncthreads();
  if (threadIdx.x == 0) bc[0] = fmaxf(fmaxf(red[0], red[1]), fmaxf(red[2], red[3]));
  __syncthreads();
  const float m = bc[0];
  float s = 0.f;
#pragma unroll
  for (int j = 0; j < 8; ++j) { e[j] = __expf(e[j] - m); s += e[j]; }
#pragma unroll
  for (int off = 32; off; off >>= 1) s += __shfl_down(s, off);
  __syncthreads();
  if (lane == 0) red[w] = s;
  __syncthreads();
  if (threadIdx.x == 0) bc[1] = 1.f / (red[0] + red[1] + red[2] + red[3]);
  __syncthreads();
  const float inv = bc[1];
  float4 oa, ob;
  oa.x = e[0] * inv; oa.y = e[1] * inv; oa.z = e[2] * inv; oa.w = e[3] * inv;
  ob.x = e[4] * inv; ob.y = e[5] * inv; ob.z = e[6] * inv; ob.w = e[7] * inv;
  *(float4*)(sc + row * 2048 + t0)     = oa;
  *(float4*)(sc + row * 2048 + t0 + 4) = ob;
  bf16x8 o8;
  o8[0] = (bf16_t)oa.x; o8[1] = (bf16_t)oa.y; o8[2] = (bf16_t)oa.z; o8[3] = (bf16_t)oa.w;
  o8[4] = (bf16_t)ob.x; o8[5] = (bf16_t)ob.y; o8[6] = (bf16_t)ob.z; o8[7] = (bf16_t)ob.w;
  *(bf16x8*)(ab + row * 2048 + t0) = o8;
}

extern "C" void kernel_launch(void* const* d_in, const int* in_sizes, int n_in,
                              void* d_out, int out_size, void* d_ws, size_t ws_size,
                              hipStream_t stream)
{
  const float* x   = (const float*)d_in[0];
  const float* Wq  = (const float*)d_in[1];
  const float* bq  = (const float*)d_in[2];
  const float* Wk  = (const float*)d_in[3];
  const float* bk  = (const float*)d_in[4];
  const float* Wv  = (const float*)d_in[5];
  const float* bv  = (const float*)d_in[6];
  const float* Wo  = (const float*)d_in[7];
  const float* bo  = (const float*)d_in[8];
  const float* g1  = (const float*)d_in[9];
  const float* be1 = (const float*)d_in[10];
  const float* g2  = (const float*)d_in[11];
  const float* be2 = (const float*)d_in[12];
  const float* W1  = (const float*)d_in[13];
  const float* b1  = (const float*)d_in[14];
  const float* W2  = (const float*)d_in[15];
  const float* b2  = (const float*)d_in[16];

  float* out   = (float*)d_out;
  float* attnF = out + 8192L * 1024;        // [4][2048][2048] fp32 (softmax out)
  bf16_t* vB   = (bf16_t*)attnF;            // scratch: row-major v (pre-scores)

  char* ws = (char*)d_ws;
  const size_t MB = 1024 * 1024;
  bf16_t* WqkvT = (bf16_t*)(ws + 0 * MB);   // [3072][1024]
  bf16_t* WoT   = (bf16_t*)(ws + 6 * MB);
  bf16_t* W1T   = (bf16_t*)(ws + 8 * MB);
  bf16_t* W2T   = (bf16_t*)(ws + 16 * MB);
  bf16_t* xn    = (bf16_t*)(ws + 24 * MB);
  bf16_t* qB    = (bf16_t*)(ws + 40 * MB);  // q, later attn_out
  bf16_t* kB    = (bf16_t*)(ws + 56 * MB);
  bf16_t* vT    = (bf16_t*)(ws + 72 * MB);  // [4][1024][2048]
  bf16_t* atB   = (bf16_t*)(ws + 88 * MB);  // S bf16, then P bf16
  float*  x2    = (float* )(ws + 120 * MB);
  bf16_t* hB    = (bf16_t*)(ws + 56 * MB);  // FFN hidden, reuses kB/vT/atB

  // all weight transposes in one dispatch
  transpose_all<<<12288, 256, 0, stream>>>(
      Wq, Wk, Wv, Wo, W1, W2, WqkvT, WoT, W1T, W2T);

  ln_kernel<<<8192, 256, 0, stream>>>(x, g1, be1, xn);

  // fused QKV: 384 blocks on 256x256 tiles, 2 blocks/CU => all co-resident
  gemm256q<<<dim3(12, 32), 512, 0, stream>>>(
      xn, WqkvT, qB, kB, vB, bq, bk, bv, 8192, 3072, 1024);

  // v -> vT; must finish before softmax overwrites vB region
  transpose_bf<<<dim3(16, 32, 4), 256, 0, stream>>>(vB, vT);

  // scores = q k^T / sqrt(D) -> atB (bf16)
  gemm8p<256, EPI_BF16_SCALE><<<dim3(8, 8, 4), 512, 0, stream>>>(
      qB, kB, nullptr, atB, nullptr,
      2048, 2048, 1024, 2048L * 1024, 2048L * 1024, 2048L * 2048, 0.03125f);

  // softmax: reads bf16 S, writes fp32 attn to d_out + bf16 P in-place
  softmax_kernel<<<8192, 256, 0, stream>>>(attnF, atB);

  // attn_out = P @ v -> ao (reuse qB)
  gemm128<EPI_BF16><<<dim3(4, 16, 4), 512, 0, stream>>>(
      atB, vT, nullptr, qB, nullptr, nullptr,
      2048, 1024, 2048, 2048L * 2048, 1024L * 2048, 2048L * 1024);

  // x2 = x + ao @ Wo + bo
  gemm128<EPI_F32_BIAS_RES><<<dim3(4, 64, 1), 512, 0, stream>>>(
      qB, WoT, x2, nullptr, bo, x,
      8192, 1024, 1024, 0, 0, 0);

  ln_kernel<<<8192, 256, 0, stream>>>(x2, g2, be2, xn);

  gemm8p<256, EPI_BF16_RELU_BIAS><<<dim3(16, 32, 1), 512, 0, stream>>>(
      xn, W1T, nullptr, hB, b1,
      8192, 4096, 1024, 0, 0, 0, 1.f);
  gemm128<EPI_F32_BIAS_RES><<<dim3(4, 64, 1), 512, 0, stream>>>(
      hB, W2T, out, nullptr, b2, x2,
      8192, 1024, 4096, 0, 0, 0);
}

// Round 13
// 390.603 us; speedup vs baseline: 1.0569x; 1.0569x over previous
//
#include <hip/hip_runtime.h>
#include <hip/hip_bf16.h>

// Transformer block: B=4, S=2048, D=1024, H=4096, fp32 in/out, bf16 MFMA compute.
// CONVERGED BEST (R10 config, 388 us measured):
//   gemm8p    : BM=256,BN=256,BK=32, 4 buffers, counted vmcnt, 1 blk/CU (scores, FFN1)
//   gemm128   : BM=128,BN=256,BK=64, 3 buffers, counted vmcnt, 1 blk/CU (PV, Wo, FFN2)
//   gemm128_32: BM=128,BN=256,BK=32, 3 buffers, counted vmcnt(3), 2 blk/CU (QKV)
//     [R12 lesson: 256^2 tile = 128 AGPR + 92 VGPR/wave -> can never fit 2
//      blocks/CU in the unified 512-reg file; BM=128 (124 regs) is the max
//      tile that co-resides 2x. Measured, not theoretical.]
// T2 swizzle (pre-swizzled global src, linear LDS dest), T5 setprio, T1 XCD swz.
// All weight transposes merged into one dispatch.

typedef __bf16 bf16_t;
typedef __bf16 bf16x8 __attribute__((ext_vector_type(8)));
typedef float  f32x4  __attribute__((ext_vector_type(4)));

#define EPI_QKV            0
#define EPI_BF16_SCALE     1
#define EPI_BF16           3
#define EPI_F32_BIAS_RES   4
#define EPI_BF16_RELU_BIAS 5

__device__ __forceinline__ void gl_lds16(const bf16_t* g, void* l) {
  __builtin_amdgcn_global_load_lds(
      (const __attribute__((address_space(1))) void*)g,
      (__attribute__((address_space(3))) void*)l, 16, 0, 0);
}

// ---------------- BM=256 x BN=256, BK=32, 4-buffer pipeline ----------------
template<int BM, int EPI>
__global__ __launch_bounds__(512, 2)
void gemm8p(const bf16_t* __restrict__ A, const bf16_t* __restrict__ B,
            float* __restrict__ Cf, bf16_t* __restrict__ Cb,
            const float* __restrict__ bias,
            int M, int N, int K, long sAb, long sBb, long sCb, float scale)
{
  constexpr int BN  = 256;
  constexpr int WTM = BM / 2;
  constexpr int MF  = WTM / 16;
  constexpr int NF  = 4;
  constexpr int LA  = BM / 128;
  constexpr int LB  = 2;
  constexpr int L   = LA + LB;
  constexpr int L0  = 2;
  constexpr int SBUF = (BM + BN) * 64;
  constexpr int W   = 2 * L;
  __shared__ __align__(16) char lds[4 * SBUF];

  const int tid = threadIdx.x;
  const int l   = tid & 63;
  const int w   = tid >> 6;
  const int wm  = w >> 2;
  const int wn  = w & 3;

  const int nx = gridDim.x, ny = gridDim.y;
  const int tot = nx * ny * gridDim.z;
  int id = blockIdx.x + nx * (blockIdx.y + ny * blockIdx.z);
  const int cpx = tot >> 3;
  int s = (id & 7) * cpx + (id >> 3);
  const int bx = s % nx; int rq = s / nx;
  const int by = rq % ny; const int bz = rq / ny;

  const bf16_t* Ab = A + (long)bz * sAb;
  const bf16_t* Bb = B + (long)bz * sBb;
  const int m0 = by * BM, n0 = bx * BN;
  const int NT = K >> 5;

  const int srow = w * 16 + (l >> 2);
  const int scol = ((l & 3) ^ ((l >> 3) & 3)) * 8;
  const bf16_t* srcA[LA]; const bf16_t* srcB[LB];
#pragma unroll
  for (int q = 0; q < LA; ++q) srcA[q] = Ab + (long)(m0 + q * 128 + srow) * K + scol;
#pragma unroll
  for (int q = 0; q < LB; ++q) srcB[q] = Bb + (long)(n0 + q * 128 + srow) * K + scol;
  const int ldsA = w * 1024;
  const int ldsB = BM * 64 + w * 1024;

  const int rA0 = wm * WTM + (l & 15);
  const int rB0 = wn * 64 + (l & 15);
  const int xoff = 16 * ((l >> 4) ^ ((l >> 1) & 3));

  f32x4 acc[MF][NF] = {};
  bf16x8 afr[MF / 2], bfr[NF];

#pragma unroll
  for (int d = 0; d < 3; ++d) {
    char* bufS = lds + d * SBUF;
    const long kst = (long)d * 32;
#pragma unroll
    for (int q = 0; q < LA; ++q) gl_lds16(srcA[q] + kst, bufS + ldsA + q * 8192);
#pragma unroll
    for (int q = 0; q < LB; ++q) gl_lds16(srcB[q] + kst, bufS + ldsB + q * 8192);
  }
  asm volatile("s_waitcnt vmcnt(%0)" :: "n"(W) : "memory");
  __builtin_amdgcn_s_barrier();
  __builtin_amdgcn_sched_barrier(0);

  for (int t = 0; t < NT; ++t) {
    const char* bufR = lds + (t & 3) * SBUF;
    char* bufS = lds + ((t + 3) & 3) * SBUF;
    const int tst = t + 3;
    const long kst = (long)((tst < NT) ? tst : (NT - 1)) * 32;

    // phase 0: B[all] + A[half0]
#pragma unroll
    for (int nf = 0; nf < NF; ++nf)
      bfr[nf] = *(const bf16x8*)(bufR + BM * 64 + (rB0 + nf * 16) * 64 + xoff);
#pragma unroll
    for (int mf = 0; mf < MF / 2; ++mf)
      afr[mf] = *(const bf16x8*)(bufR + (rA0 + mf * 16) * 64 + xoff);
#pragma unroll
    for (int q = 0; q < L0; ++q) {
      if (q < LA) gl_lds16(srcA[q] + kst, bufS + ldsA + q * 8192);
      else        gl_lds16(srcB[q - LA] + kst, bufS + ldsB + (q - LA) * 8192);
    }
    __builtin_amdgcn_s_barrier();
    __builtin_amdgcn_s_setprio(1);
#pragma unroll
    for (int mf = 0; mf < MF / 2; ++mf)
#pragma unroll
      for (int nf = 0; nf < NF; ++nf)
        acc[mf][nf] = __builtin_amdgcn_mfma_f32_16x16x32_bf16(afr[mf], bfr[nf], acc[mf][nf], 0, 0, 0);
    __builtin_amdgcn_s_setprio(0);
    __builtin_amdgcn_s_barrier();

    // phase 1: A[half1]
#pragma unroll
    for (int mf = 0; mf < MF / 2; ++mf)
      afr[mf] = *(const bf16x8*)(bufR + (rA0 + (MF / 2 + mf) * 16) * 64 + xoff);
#pragma unroll
    for (int q = L0; q < L; ++q) {
      if (q < LA) gl_lds16(srcA[q] + kst, bufS + ldsA + q * 8192);
      else        gl_lds16(srcB[q - LA] + kst, bufS + ldsB + (q - LA) * 8192);
    }
    __builtin_amdgcn_s_barrier();
    __builtin_amdgcn_s_setprio(1);
#pragma unroll
    for (int mf = 0; mf < MF / 2; ++mf)
#pragma unroll
      for (int nf = 0; nf < NF; ++nf)
        acc[MF / 2 + mf][nf] = __builtin_amdgcn_mfma_f32_16x16x32_bf16(afr[mf], bfr[nf], acc[MF / 2 + mf][nf], 0, 0, 0);
    __builtin_amdgcn_s_setprio(0);
    asm volatile("s_waitcnt vmcnt(%0)" :: "n"(W) : "memory");
    __builtin_amdgcn_s_barrier();
    __builtin_amdgcn_sched_barrier(0);
  }
  asm volatile("s_waitcnt vmcnt(0)" ::: "memory");

  const int colB0 = n0 + wn * 64 + (l & 15);
  const int rowB0 = m0 + wm * WTM + ((l >> 4) << 2);
#pragma unroll
  for (int mi = 0; mi < MF; ++mi) {
#pragma unroll
    for (int ni = 0; ni < NF; ++ni) {
      const int col = colB0 + ni * 16;
#pragma unroll
      for (int j = 0; j < 4; ++j) {
        const int row = rowB0 + mi * 16 + j;
        const float v = acc[mi][ni][j];
        if constexpr (EPI == EPI_BF16_SCALE) {
          Cb[sCb * bz + (long)row * N + col] = (bf16_t)(v * scale);
        } else { // EPI_BF16_RELU_BIAS
          const float u = v + bias[col];
          Cb[(long)row * N + col] = (bf16_t)(u > 0.f ? u : 0.f);
        }
      }
    }
  }
}

// ---------------- BM=128 x BN=256, BK=64, 3-buffer pipeline ----------------
template<int EPI>
__global__ __launch_bounds__(512, 1)
void gemm128(const bf16_t* __restrict__ A, const bf16_t* __restrict__ B,
             float* __restrict__ Cf, bf16_t* __restrict__ Cb,
             const float* __restrict__ bias, const float* __restrict__ resid,
             int M, int N, int K, long sAb, long sBb, long sCb)
{
  constexpr int SBUF = 49152;
  __shared__ __align__(16) char lds[3 * SBUF];
  const int tid = threadIdx.x;
  const int l   = tid & 63;
  const int w   = tid >> 6;
  const int wm  = w >> 2, wn = w & 3;

  const int nx = gridDim.x, ny = gridDim.y;
  const int tot = nx * ny * gridDim.z;
  int id = blockIdx.x + nx * (blockIdx.y + ny * blockIdx.z);
  const int cpx = tot >> 3;
  int sid = (id & 7) * cpx + (id >> 3);
  const int bx = sid % nx; int rq = sid / nx;
  const int by = rq % ny; const int bz = rq / ny;

  const bf16_t* Ab = A + (long)bz * sAb;
  const bf16_t* Bb = B + (long)bz * sBb;
  const int m0 = by * 128, n0 = bx * 256;
  const int NT = K >> 6;

  const int scol = ((l & 7) ^ (l >> 3)) * 8;
  const bf16_t* srcA = Ab + (long)(m0 + 16 * w + (l >> 3)) * K + scol;
  const bf16_t* srcB = Bb + (long)(n0 + 32 * w + (l >> 3)) * K + scol;
  const int dA = w * 2048 + l * 16;
  const int dB = 16384 + w * 4096 + l * 16;

  const int rA = wm * 64 + (l & 15);
  const int rB = wn * 64 + (l & 15);
  const int xo = ((l >> 4) ^ (l & 7)) * 16;
  const int aoff = rA * 128 + xo;
  const int boff = 16384 + rB * 128 + xo;

  f32x4 acc[4][4] = {};
  bf16x8 af[4], bv[4];

  {
    char* b0 = lds; char* b1 = lds + SBUF;
#pragma unroll
    for (int q = 0; q < 2; ++q) gl_lds16(srcA + (long)q * 8 * K, b0 + dA + q * 1024);
#pragma unroll
    for (int q = 0; q < 4; ++q) gl_lds16(srcB + (long)q * 8 * K, b0 + dB + q * 1024);
#pragma unroll
    for (int q = 0; q < 2; ++q) gl_lds16(srcA + (long)q * 8 * K + 64, b1 + dA + q * 1024);
#pragma unroll
    for (int q = 0; q < 4; ++q) gl_lds16(srcB + (long)q * 8 * K + 64, b1 + dB + q * 1024);
  }
  asm volatile("s_waitcnt vmcnt(6)" ::: "memory");
  __builtin_amdgcn_s_barrier();
  __builtin_amdgcn_sched_barrier(0);

  int ir = 0, is = 2;
  for (int t = 0; t < NT; ++t) {
    const char* bufR = lds + ir * SBUF;
    char* bufS = lds + is * SBUF;
    const int tst = (t + 2 < NT) ? t + 2 : NT - 1;
    const long kst = (long)tst * 64;

#pragma unroll
    for (int nf = 0; nf < 4; ++nf) bv[nf] = *(const bf16x8*)(bufR + boff + nf * 2048);
#pragma unroll
    for (int mf = 0; mf < 4; ++mf) af[mf] = *(const bf16x8*)(bufR + aoff + mf * 2048);
    gl_lds16(srcA + kst,                 bufS + dA);
    gl_lds16(srcA + (long)8 * K + kst,   bufS + dA + 1024);
    gl_lds16(srcB + kst,                 bufS + dB);
    __builtin_amdgcn_s_barrier();
    __builtin_amdgcn_s_setprio(1);
#pragma unroll
    for (int mf = 0; mf < 4; ++mf)
#pragma unroll
      for (int nf = 0; nf < 4; ++nf)
        acc[mf][nf] = __builtin_amdgcn_mfma_f32_16x16x32_bf16(af[mf], bv[nf], acc[mf][nf], 0, 0, 0);
    __builtin_amdgcn_s_setprio(0);
    __builtin_amdgcn_s_barrier();

#pragma unroll
    for (int nf = 0; nf < 4; ++nf) bv[nf] = *(const bf16x8*)(bufR + ((boff + nf * 2048) ^ 64));
#pragma unroll
    for (int mf = 0; mf < 4; ++mf) af[mf] = *(const bf16x8*)(bufR + ((aoff + mf * 2048) ^ 64));
    gl_lds16(srcB + (long)8 * K + kst,   bufS + dB + 1024);
    gl_lds16(srcB + (long)16 * K + kst,  bufS + dB + 2048);
    gl_lds16(srcB + (long)24 * K + kst,  bufS + dB + 3072);
    __builtin_amdgcn_s_barrier();
    __builtin_amdgcn_s_setprio(1);
#pragma unroll
    for (int mf = 0; mf < 4; ++mf)
#pragma unroll
      for (int nf = 0; nf < 4; ++nf)
        acc[mf][nf] = __builtin_amdgcn_mfma_f32_16x16x32_bf16(af[mf], bv[nf], acc[mf][nf], 0, 0, 0);
    __builtin_amdgcn_s_setprio(0);
    asm volatile("s_waitcnt vmcnt(6)" ::: "memory");
    __builtin_amdgcn_s_barrier();
    __builtin_amdgcn_sched_barrier(0);
    ir = (ir == 2) ? 0 : ir + 1;
    is = (is == 2) ? 0 : is + 1;
  }
  asm volatile("s_waitcnt vmcnt(0)" ::: "memory");

  const int colB0 = n0 + wn * 64 + (l & 15);
  const int rowB0 = m0 + wm * 64 + ((l >> 4) << 2);
#pragma unroll
  for (int mi = 0; mi < 4; ++mi) {
#pragma unroll
    for (int ni = 0; ni < 4; ++ni) {
      const int col = colB0 + ni * 16;
#pragma unroll
      for (int j = 0; j < 4; ++j) {
        const int row = rowB0 + mi * 16 + j;
        const float v = acc[mi][ni][j];
        if constexpr (EPI == EPI_BF16) {
          Cb[sCb * bz + (long)row * N + col] = (bf16_t)v;
        } else { // EPI_F32_BIAS_RES
          Cf[(long)row * N + col] = v + bias[col] + resid[(long)row * N + col];
        }
      }
    }
  }
}

// -- BM=128 x BN=256, BK=32, 3-buffer, counted vmcnt(3), 2 blocks/CU (QKV) --
__global__ __launch_bounds__(512, 2)
void gemm128_32(const bf16_t* __restrict__ A, const bf16_t* __restrict__ B,
                bf16_t* __restrict__ Cb, bf16_t* __restrict__ Cb2,
                bf16_t* __restrict__ Cb3,
                const float* __restrict__ bias, const float* __restrict__ bias2,
                const float* __restrict__ bias3, int M, int N, int K)
{
  constexpr int SBUF = 24576;  // A 128x32 (8KB) + B 256x32 (16KB)
  __shared__ __align__(16) char lds[3 * SBUF];
  const int tid = threadIdx.x;
  const int l   = tid & 63;
  const int w   = tid >> 6;
  const int wm  = w >> 2, wn = w & 3;

  const int nx = gridDim.x, ny = gridDim.y;
  const int tot = nx * ny;
  int id = blockIdx.x + nx * blockIdx.y;
  const int cpx = tot >> 3;
  int sid = (id & 7) * cpx + (id >> 3);
  const int bx = sid % nx;
  const int by = sid / nx;

  const int m0 = by * 128, n0 = bx * 256;
  const int NT = K >> 5;

  const int srow = (l >> 2);
  const int scol = ((l & 3) ^ ((l >> 3) & 3)) * 8;
  const bf16_t* srcA = A + (long)(m0 + w * 16 + srow) * K + scol;
  const bf16_t* srcB0 = B + (long)(n0 + w * 32 + srow) * K + scol;
  const bf16_t* srcB1 = srcB0 + (long)16 * K;
  const int dA = w * 1024 + l * 16;
  const int dB = 8192 + w * 2048 + l * 16;

  const int rA = wm * 64 + (l & 15);
  const int rB = wn * 64 + (l & 15);
  const int xoff = 16 * ((l >> 4) ^ ((l >> 1) & 3));
  const int aoff = rA * 64 + xoff;
  const int boff = 8192 + rB * 64 + xoff;

  f32x4 acc[4][4] = {};
  bf16x8 af[4], bv[4];

  // prologue: stage tiles 0,1 (3 loads/wave each)
  gl_lds16(srcA,       lds + dA);
  gl_lds16(srcB0,      lds + dB);
  gl_lds16(srcB1,      lds + dB + 1024);
  gl_lds16(srcA + 32,  lds + SBUF + dA);
  gl_lds16(srcB0 + 32, lds + SBUF + dB);
  gl_lds16(srcB1 + 32, lds + SBUF + dB + 1024);
  asm volatile("s_waitcnt vmcnt(3)" ::: "memory");
  __builtin_amdgcn_s_barrier();
  __builtin_amdgcn_sched_barrier(0);

  int ir = 0, is = 2;
  for (int t = 0; t < NT; ++t) {
    const char* bufR = lds + ir * SBUF;
    char* bufS = lds + is * SBUF;
    const long kst = (long)((t + 2 < NT) ? t + 2 : NT - 1) * 32;

#pragma unroll
    for (int nf = 0; nf < 4; ++nf) bv[nf] = *(const bf16x8*)(bufR + boff + nf * 1024);
#pragma unroll
    for (int mf = 0; mf < 4; ++mf) af[mf] = *(const bf16x8*)(bufR + aoff + mf * 1024);
    gl_lds16(srcA + kst, bufS + dA);
    gl_lds16(srcB0 + kst, bufS + dB);
    gl_lds16(srcB1 + kst, bufS + dB + 1024);
    __builtin_amdgcn_s_setprio(1);
#pragma unroll
    for (int mf = 0; mf < 4; ++mf)
#pragma unroll
      for (int nf = 0; nf < 4; ++nf)
        acc[mf][nf] = __builtin_amdgcn_mfma_f32_16x16x32_bf16(af[mf], bv[nf], acc[mf][nf], 0, 0, 0);
    __builtin_amdgcn_s_setprio(0);
    asm volatile("s_waitcnt vmcnt(3)" ::: "memory");
    __builtin_amdgcn_s_barrier();
    __builtin_amdgcn_sched_barrier(0);
    ir = (ir == 2) ? 0 : ir + 1;
    is = (is == 2) ? 0 : is + 1;
  }
  asm volatile("s_waitcnt vmcnt(0)" ::: "memory");

  const int colB0 = n0 + wn * 64 + (l & 15);
  const int rowB0 = m0 + wm * 64 + ((l >> 4) << 2);
#pragma unroll
  for (int mi = 0; mi < 4; ++mi) {
#pragma unroll
    for (int ni = 0; ni < 4; ++ni) {
      const int col = colB0 + ni * 16;
#pragma unroll
      for (int j = 0; j < 4; ++j) {
        const int row = rowB0 + mi * 16 + j;
        const float v = acc[mi][ni][j];
        if (col < 1024)      Cb [(long)row * 1024 + col]        = (bf16_t)(v + bias[col]);
        else if (col < 2048) Cb2[(long)row * 1024 + col - 1024] = (bf16_t)(v + bias2[col - 1024]);
        else                 Cb3[(long)row * 1024 + col - 2048] = (bf16_t)(v + bias3[col - 2048]);
      }
    }
  }
}

// bf16 transpose: V [4][2048][1024] -> VT [4][1024][2048]. 64x64 tiles.
__global__ __launch_bounds__(256)
void transpose_bf(const bf16_t* __restrict__ V, bf16_t* __restrict__ VT)
{
  __shared__ __align__(16) bf16_t t[64][72];
  const int b = blockIdx.z;
  const int t0 = blockIdx.y * 64, d0 = blockIdx.x * 64;
  const int r = threadIdx.x >> 3;
  const int c = (threadIdx.x & 7) * 8;
  const bf16_t* src = V + ((long)b * 2048 + t0) * 1024 + d0;
#pragma unroll
  for (int h = 0; h < 2; ++h)
    *(bf16x8*)&t[r + 32 * h][c] = *(const bf16x8*)(src + (long)(r + 32 * h) * 1024 + c);
  __syncthreads();
  bf16_t* dst = VT + ((long)b * 1024 + d0) * 2048 + t0;
#pragma unroll
  for (int h = 0; h < 2; ++h) {
    const int d = r + 32 * h;
    bf16x8 o;
#pragma unroll
    for (int j = 0; j < 8; ++j) o[j] = t[c + j][d];
    *(bf16x8*)(dst + (long)d * 2048 + c) = o;
  }
}

// All 6 weight transposes in one dispatch. Flat grid 12288 blocks.
__global__ __launch_bounds__(256)
void transpose_all(const float* __restrict__ Wq, const float* __restrict__ Wk,
                   const float* __restrict__ Wv, const float* __restrict__ Wo,
                   const float* __restrict__ W1, const float* __restrict__ W2,
                   bf16_t* __restrict__ WqkvT, bf16_t* __restrict__ WoT,
                   bf16_t* __restrict__ W1T, bf16_t* __restrict__ W2T)
{
  const int id = blockIdx.x;
  const float* W; bf16_t* WT; int R, C, cb, rb;
  if (id < 4096) {
    const int wsel = id >> 10, loc = id & 1023;
    cb = loc & 31; rb = loc >> 5; R = 1024; C = 1024;
    if (wsel == 0)      { W = Wq; WT = WqkvT; }
    else if (wsel == 1) { W = Wk; WT = WqkvT + 1024L * 1024; }
    else if (wsel == 2) { W = Wv; WT = WqkvT + 2048L * 1024; }
    else                { W = Wo; WT = WoT; }
  } else if (id < 8192) {
    const int loc = id - 4096;
    cb = loc & 127; rb = loc >> 7; R = 1024; C = 4096;
    W = W1; WT = W1T;
  } else {
    const int loc = id - 8192;
    cb = loc & 31; rb = loc >> 5; R = 4096; C = 1024;
    W = W2; WT = W2T;
  }
  __shared__ float t[32][33];
  const int c0 = cb * 32, r0 = rb * 32;
  const int tx = threadIdx.x & 31, ty = threadIdx.x >> 5;
#pragma unroll
  for (int i = 0; i < 32; i += 8)
    t[ty + i][tx] = W[(long)(r0 + ty + i) * C + c0 + tx];
  __syncthreads();
#pragma unroll
  for (int i = 0; i < 32; i += 8)
    WT[(long)(c0 + ty + i) * R + r0 + tx] = (bf16_t)t[tx][ty + i];
}

// LayerNorm over D=1024, one block (256 thr) per row, out = bf16.
__global__ __launch_bounds__(256)
void ln_kernel(const float* __restrict__ x, const float* __restrict__ g,
               const float* __restrict__ be, bf16_t* __restrict__ out)
{
  const long row = blockIdx.x;
  const float4 v = *(const float4*)(x + row * 1024 + threadIdx.x * 4);
  float s  = v.x + v.y + v.z + v.w;
  float s2 = v.x * v.x + v.y * v.y + v.z * v.z + v.w * v.w;
  __shared__ float red[10];
  const int lane = threadIdx.x & 63, w = threadIdx.x >> 6;
#pragma unroll
  for (int off = 32; off; off >>= 1) {
    s  += __shfl_down(s, off);
    s2 += __shfl_down(s2, off);
  }
  if (lane == 0) { red[w] = s; red[4 + w] = s2; }
  __syncthreads();
  if (threadIdx.x == 0) {
    const float ts = red[0] + red[1] + red[2] + red[3];
    const float t2 = red[4] + red[5] + red[6] + red[7];
    const float mu = ts * (1.f / 1024.f);
    const float var = t2 * (1.f / 1024.f) - mu * mu;
    red[8] = mu;
    red[9] = rsqrtf(var + 1e-5f);
  }
  __syncthreads();
  const float mu = red[8], rinv = red[9];
  const int c = threadIdx.x * 4;
  const float4 gv = *(const float4*)(g + c);
  const float4 bvv = *(const float4*)(be + c);
  bf16_t* o = out + row * 1024 + c;
  o[0] = (bf16_t)((v.x - mu) * rinv * gv.x + bvv.x);
  o[1] = (bf16_t)((v.y - mu) * rinv * gv.y + bvv.y);
  o[2] = (bf16_t)((v.z - mu) * rinv * gv.z + bvv.z);
  o[3] = (bf16_t)((v.w - mu) * rinv * gv.w + bvv.w);
}

// Row softmax over S=2048: reads bf16 S from ab, writes fp32 attn to sc and
// bf16 P in-place to ab. One block (256 thr) per row.
__global__ __launch_bounds__(256)
void softmax_kernel(float* __restrict__ sc, bf16_t* __restrict__ ab)
{
  const long row = blockIdx.x;
  const int t0 = threadIdx.x * 8;
  const bf16x8 v8 = *(const bf16x8*)(ab + row * 2048 + t0);
  float e[8];
#pragma unroll
  for (int j = 0; j < 8; ++j) e[j] = (float)v8[j];
  float mx = fmaxf(fmaxf(fmaxf(e[0], e[1]), fmaxf(e[2], e[3])),
                   fmaxf(fmaxf(e[4], e[5]), fmaxf(e[6], e[7])));
  __shared__ float red[4];
  __shared__ float bc[2];
  const int lane = threadIdx.x & 63, w = threadIdx.x >> 6;
#pragma unroll
  for (int off = 32; off; off >>= 1) mx = fmaxf(mx, __shfl_down(mx, off));
  if (lane == 0) red[w] = mx;
  __syncthreads();
  if (threadIdx.x == 0) bc[0] = fmaxf(fmaxf(red[0], red[1]), fmaxf(red[2], red[3]));
  __syncthreads();
  const float m = bc[0];
  float s = 0.f;
#pragma unroll
  for (int j = 0; j < 8; ++j) { e[j] = __expf(e[j] - m); s += e[j]; }
#pragma unroll
  for (int off = 32; off; off >>= 1) s += __shfl_down(s, off);
  __syncthreads();
  if (lane == 0) red[w] = s;
  __syncthreads();
  if (threadIdx.x == 0) bc[1] = 1.f / (red[0] + red[1] + red[2] + red[3]);
  __syncthreads();
  const float inv = bc[1];
  float4 oa, ob;
  oa.x = e[0] * inv; oa.y = e[1] * inv; oa.z = e[2] * inv; oa.w = e[3] * inv;
  ob.x = e[4] * inv; ob.y = e[5] * inv; ob.z = e[6] * inv; ob.w = e[7] * inv;
  *(float4*)(sc + row * 2048 + t0)     = oa;
  *(float4*)(sc + row * 2048 + t0 + 4) = ob;
  bf16x8 o8;
  o8[0] = (bf16_t)oa.x; o8[1] = (bf16_t)oa.y; o8[2] = (bf16_t)oa.z; o8[3] = (bf16_t)oa.w;
  o8[4] = (bf16_t)ob.x; o8[5] = (bf16_t)ob.y; o8[6] = (bf16_t)ob.z; o8[7] = (bf16_t)ob.w;
  *(bf16x8*)(ab + row * 2048 + t0) = o8;
}

extern "C" void kernel_launch(void* const* d_in, const int* in_sizes, int n_in,
                              void* d_out, int out_size, void* d_ws, size_t ws_size,
                              hipStream_t stream)
{
  const float* x   = (const float*)d_in[0];
  const float* Wq  = (const float*)d_in[1];
  const float* bq  = (const float*)d_in[2];
  const float* Wk  = (const float*)d_in[3];
  const float* bk  = (const float*)d_in[4];
  const float* Wv  = (const float*)d_in[5];
  const float* bv  = (const float*)d_in[6];
  const float* Wo  = (const float*)d_in[7];
  const float* bo  = (const float*)d_in[8];
  const float* g1  = (const float*)d_in[9];
  const float* be1 = (const float*)d_in[10];
  const float* g2  = (const float*)d_in[11];
  const float* be2 = (const float*)d_in[12];
  const float* W1  = (const float*)d_in[13];
  const float* b1  = (const float*)d_in[14];
  const float* W2  = (const float*)d_in[15];
  const float* b2  = (const float*)d_in[16];

  float* out   = (float*)d_out;
  float* attnF = out + 8192L * 1024;        // [4][2048][2048] fp32 (softmax out)
  bf16_t* vB   = (bf16_t*)attnF;            // scratch: row-major v (pre-scores)

  char* ws = (char*)d_ws;
  const size_t MB = 1024 * 1024;
  bf16_t* WqkvT = (bf16_t*)(ws + 0 * MB);   // [3072][1024]
  bf16_t* WoT   = (bf16_t*)(ws + 6 * MB);
  bf16_t* W1T   = (bf16_t*)(ws + 8 * MB);
  bf16_t* W2T   = (bf16_t*)(ws + 16 * MB);
  bf16_t* xn    = (bf16_t*)(ws + 24 * MB);
  bf16_t* qB    = (bf16_t*)(ws + 40 * MB);  // q, later attn_out
  bf16_t* kB    = (bf16_t*)(ws + 56 * MB);
  bf16_t* vT    = (bf16_t*)(ws + 72 * MB);  // [4][1024][2048]
  bf16_t* atB   = (bf16_t*)(ws + 88 * MB);  // S bf16, then P bf16
  float*  x2    = (float* )(ws + 120 * MB);
  bf16_t* hB    = (bf16_t*)(ws + 56 * MB);  // FFN hidden, reuses kB/vT/atB

  // all weight transposes in one dispatch
  transpose_all<<<12288, 256, 0, stream>>>(
      Wq, Wk, Wv, Wo, W1, W2, WqkvT, WoT, W1T, W2T);

  ln_kernel<<<8192, 256, 0, stream>>>(x, g1, be1, xn);

  // fused QKV: 768 blocks, 2 blocks/CU, 3-buffer counted-vmcnt pipeline
  gemm128_32<<<dim3(12, 64), 512, 0, stream>>>(
      xn, WqkvT, qB, kB, vB, bq, bk, bv, 8192, 3072, 1024);

  // v -> vT; must finish before softmax overwrites vB region
  transpose_bf<<<dim3(16, 32, 4), 256, 0, stream>>>(vB, vT);

  // scores = q k^T / sqrt(D) -> atB (bf16)
  gemm8p<256, EPI_BF16_SCALE><<<dim3(8, 8, 4), 512, 0, stream>>>(
      qB, kB, nullptr, atB, nullptr,
      2048, 2048, 1024, 2048L * 1024, 2048L * 1024, 2048L * 2048, 0.03125f);

  // softmax: reads bf16 S, writes fp32 attn to d_out + bf16 P in-place
  softmax_kernel<<<8192, 256, 0, stream>>>(attnF, atB);

  // attn_out = P @ v -> ao (reuse qB)
  gemm128<EPI_BF16><<<dim3(4, 16, 4), 512, 0, stream>>>(
      atB, vT, nullptr, qB, nullptr, nullptr,
      2048, 1024, 2048, 2048L * 2048, 1024L * 2048, 2048L * 1024);

  // x2 = x + ao @ Wo + bo
  gemm128<EPI_F32_BIAS_RES><<<dim3(4, 64, 1), 512, 0, stream>>>(
      qB, WoT, x2, nullptr, bo, x,
      8192, 1024, 1024, 0, 0, 0);

  ln_kernel<<<8192, 256, 0, stream>>>(x2, g2, be2, xn);

  gemm8p<256, EPI_BF16_RELU_BIAS><<<dim3(16, 32, 1), 512, 0, stream>>>(
      xn, W1T, nullptr, hB, b1,
      8192, 4096, 1024, 0, 0, 0, 1.f);
  gemm128<EPI_F32_BIAS_RES><<<dim3(4, 64, 1), 512, 0, stream>>>(
      hB, W2T, out, nullptr, b2, x2,
      8192, 1024, 4096, 0, 0, 0);
}

// Round 14
// 385.740 us; speedup vs baseline: 1.0702x; 1.0126x over previous
//
#include <hip/hip_runtime.h>
#include <hip/hip_bf16.h>

// Transformer block: B=4, S=2048, D=1024, H=4096, fp32 in/out, bf16 MFMA compute.
//   gemm8p    : BM=256,BN=256,BK=32, 4 buffers, READ-AHEAD phases (operands ds_read
//               one phase before consumption, m201 mechanism), vmcnt(4)/tile,
//               1 blk/CU (scores, FFN1)
//   gemm128   : BM=128,BN=256,BK=64, 3 buffers, counted vmcnt, 1 blk/CU (PV, Wo, FFN2)
//   gemm128_32: BM=128,BN=256,BK=32, 3 buffers, counted vmcnt(3), 2 blk/CU (QKV)
// T2 swizzle (pre-swizzled global src, linear LDS dest), T5 setprio, T1 XCD swz.

typedef __bf16 bf16_t;
typedef __bf16 bf16x8 __attribute__((ext_vector_type(8)));
typedef float  f32x4  __attribute__((ext_vector_type(4)));

#define EPI_BF16_SCALE     1
#define EPI_BF16           3
#define EPI_F32_BIAS_RES   4
#define EPI_BF16_RELU_BIAS 5

__device__ __forceinline__ void gl_lds16(const bf16_t* g, void* l) {
  __builtin_amdgcn_global_load_lds(
      (const __attribute__((address_space(1))) void*)g,
      (__attribute__((address_space(3))) void*)l, 16, 0, 0);
}

// ------- BM=256 x BN=256, BK=32, 4-buffer, READ-AHEAD phase pipeline -------
template<int BM, int EPI>
__global__ __launch_bounds__(512, 2)
void gemm8p(const bf16_t* __restrict__ A, const bf16_t* __restrict__ B,
            float* __restrict__ Cf, bf16_t* __restrict__ Cb,
            const float* __restrict__ bias,
            int M, int N, int K, long sAb, long sBb, long sCb, float scale)
{
  static_assert(BM == 256, "read-ahead body assumes MF=8");
  constexpr int BN  = 256;
  constexpr int WTM = BM / 2;
  constexpr int MF  = WTM / 16;   // 8
  constexpr int NF  = 4;
  constexpr int SBUF = (BM + BN) * 64;
  __shared__ __align__(16) char lds[4 * SBUF];

  const int tid = threadIdx.x;
  const int l   = tid & 63;
  const int w   = tid >> 6;
  const int wm  = w >> 2;
  const int wn  = w & 3;

  const int nx = gridDim.x, ny = gridDim.y;
  const int tot = nx * ny * gridDim.z;
  int id = blockIdx.x + nx * (blockIdx.y + ny * blockIdx.z);
  const int cpx = tot >> 3;
  int s = (id & 7) * cpx + (id >> 3);
  const int bx = s % nx; int rq = s / nx;
  const int by = rq % ny; const int bz = rq / ny;

  const bf16_t* Ab = A + (long)bz * sAb;
  const bf16_t* Bb = B + (long)bz * sBb;
  const int m0 = by * BM, n0 = bx * BN;
  const int NT = K >> 5;   // always even here (K=1024)

  const int srow = w * 16 + (l >> 2);
  const int scol = ((l & 3) ^ ((l >> 3) & 3)) * 8;
  const bf16_t* srcA[2]; const bf16_t* srcB[2];
#pragma unroll
  for (int q = 0; q < 2; ++q) srcA[q] = Ab + (long)(m0 + q * 128 + srow) * K + scol;
#pragma unroll
  for (int q = 0; q < 2; ++q) srcB[q] = Bb + (long)(n0 + q * 128 + srow) * K + scol;
  const int ldsA = w * 1024;
  const int ldsB = BM * 64 + w * 1024;

  const int rA0 = wm * WTM + (l & 15);
  const int rB0 = wn * 64 + (l & 15);
  const int xoff = 16 * ((l >> 4) ^ ((l >> 1) & 3));

  f32x4 acc[MF][NF] = {};
  bf16x8 a0[4], a1[4], bva[NF], bvb[NF];

  // prologue: stage tiles 0..2 (4 loads each)
#pragma unroll
  for (int d = 0; d < 3; ++d) {
    char* bufS = lds + d * SBUF;
    const long kst = (long)d * 32;
#pragma unroll
    for (int q = 0; q < 2; ++q) gl_lds16(srcA[q] + kst, bufS + ldsA + q * 8192);
#pragma unroll
    for (int q = 0; q < 2; ++q) gl_lds16(srcB[q] + kst, bufS + ldsB + q * 8192);
  }
  // retire tiles 0 AND 1 (12 in flight -> 4): tile1 is read-ahead at ph0(0)
  asm volatile("s_waitcnt vmcnt(4)" ::: "memory");
  __builtin_amdgcn_s_barrier();
  __builtin_amdgcn_sched_barrier(0);

  // pre-read tile-0 operands: A-low and B
#pragma unroll
  for (int mf = 0; mf < 4; ++mf)
    a0[mf] = *(const bf16x8*)(lds + (rA0 + mf * 16) * 64 + xoff);
#pragma unroll
  for (int nf = 0; nf < NF; ++nf)
    bva[nf] = *(const bf16x8*)(lds + BM * 64 + (rB0 + nf * 16) * 64 + xoff);

  auto step = [&](int t, bf16x8 (&BV)[NF], bf16x8 (&BNx)[NF]) {
    const char* bufR = lds + (t & 3) * SBUF;        // tile t
    const char* bufN = lds + ((t + 1) & 3) * SBUF;  // tile t+1 (read-ahead)
    char* bufS = lds + ((t + 3) & 3) * SBUF;
    const int tst = t + 3;
    const long kst = (long)((tst < NT) ? tst : (NT - 1)) * 32;

    // ph0: issue reads A-high[t] + B[t+1]; stage A-chunks; MFMA Mlow = a0 x BV
#pragma unroll
    for (int mf = 0; mf < 4; ++mf)
      a1[mf] = *(const bf16x8*)(bufR + (rA0 + (4 + mf) * 16) * 64 + xoff);
#pragma unroll
    for (int nf = 0; nf < NF; ++nf)
      BNx[nf] = *(const bf16x8*)(bufN + BM * 64 + (rB0 + nf * 16) * 64 + xoff);
    gl_lds16(srcA[0] + kst, bufS + ldsA);
    gl_lds16(srcA[1] + kst, bufS + ldsA + 8192);
    __builtin_amdgcn_s_barrier();
    __builtin_amdgcn_s_setprio(1);
#pragma unroll
    for (int mf = 0; mf < 4; ++mf)
#pragma unroll
      for (int nf = 0; nf < NF; ++nf)
        acc[mf][nf] = __builtin_amdgcn_mfma_f32_16x16x32_bf16(a0[mf], BV[nf], acc[mf][nf], 0, 0, 0);
    __builtin_amdgcn_s_setprio(0);
    __builtin_amdgcn_s_barrier();

    // ph1: issue reads A-low[t+1]; stage B-chunks; MFMA Mhigh = a1 x BV
#pragma unroll
    for (int mf = 0; mf < 4; ++mf)
      a0[mf] = *(const bf16x8*)(bufN + (rA0 + mf * 16) * 64 + xoff);
    gl_lds16(srcB[0] + kst, bufS + ldsB);
    gl_lds16(srcB[1] + kst, bufS + ldsB + 8192);
    __builtin_amdgcn_s_barrier();
    __builtin_amdgcn_s_setprio(1);
#pragma unroll
    for (int mf = 0; mf < 4; ++mf)
#pragma unroll
      for (int nf = 0; nf < NF; ++nf)
        acc[4 + mf][nf] = __builtin_amdgcn_mfma_f32_16x16x32_bf16(a1[mf], BV[nf], acc[4 + mf][nf], 0, 0, 0);
    __builtin_amdgcn_s_setprio(0);
    // retire tile t+2's staged loads (8 in flight -> 4) before next tile
    asm volatile("s_waitcnt vmcnt(4)" ::: "memory");
    __builtin_amdgcn_s_barrier();
    __builtin_amdgcn_sched_barrier(0);
  };

  for (int t = 0; t < NT; t += 2) {
    step(t,     bva, bvb);
    step(t + 1, bvb, bva);
  }
  asm volatile("s_waitcnt vmcnt(0)" ::: "memory");

  const int colB0 = n0 + wn * 64 + (l & 15);
  const int rowB0 = m0 + wm * WTM + ((l >> 4) << 2);
#pragma unroll
  for (int mi = 0; mi < MF; ++mi) {
#pragma unroll
    for (int ni = 0; ni < NF; ++ni) {
      const int col = colB0 + ni * 16;
#pragma unroll
      for (int j = 0; j < 4; ++j) {
        const int row = rowB0 + mi * 16 + j;
        const float v = acc[mi][ni][j];
        if constexpr (EPI == EPI_BF16_SCALE) {
          Cb[sCb * bz + (long)row * N + col] = (bf16_t)(v * scale);
        } else { // EPI_BF16_RELU_BIAS
          const float u = v + bias[col];
          Cb[(long)row * N + col] = (bf16_t)(u > 0.f ? u : 0.f);
        }
      }
    }
  }
}

// ---------------- BM=128 x BN=256, BK=64, 3-buffer pipeline ----------------
template<int EPI>
__global__ __launch_bounds__(512, 1)
void gemm128(const bf16_t* __restrict__ A, const bf16_t* __restrict__ B,
             float* __restrict__ Cf, bf16_t* __restrict__ Cb,
             const float* __restrict__ bias, const float* __restrict__ resid,
             int M, int N, int K, long sAb, long sBb, long sCb)
{
  constexpr int SBUF = 49152;
  __shared__ __align__(16) char lds[3 * SBUF];
  const int tid = threadIdx.x;
  const int l   = tid & 63;
  const int w   = tid >> 6;
  const int wm  = w >> 2, wn = w & 3;

  const int nx = gridDim.x, ny = gridDim.y;
  const int tot = nx * ny * gridDim.z;
  int id = blockIdx.x + nx * (blockIdx.y + ny * blockIdx.z);
  const int cpx = tot >> 3;
  int sid = (id & 7) * cpx + (id >> 3);
  const int bx = sid % nx; int rq = sid / nx;
  const int by = rq % ny; const int bz = rq / ny;

  const bf16_t* Ab = A + (long)bz * sAb;
  const bf16_t* Bb = B + (long)bz * sBb;
  const int m0 = by * 128, n0 = bx * 256;
  const int NT = K >> 6;

  const int scol = ((l & 7) ^ (l >> 3)) * 8;
  const bf16_t* srcA = Ab + (long)(m0 + 16 * w + (l >> 3)) * K + scol;
  const bf16_t* srcB = Bb + (long)(n0 + 32 * w + (l >> 3)) * K + scol;
  const int dA = w * 2048 + l * 16;
  const int dB = 16384 + w * 4096 + l * 16;

  const int rA = wm * 64 + (l & 15);
  const int rB = wn * 64 + (l & 15);
  const int xo = ((l >> 4) ^ (l & 7)) * 16;
  const int aoff = rA * 128 + xo;
  const int boff = 16384 + rB * 128 + xo;

  f32x4 acc[4][4] = {};
  bf16x8 af[4], bv[4];

  {
    char* b0 = lds; char* b1 = lds + SBUF;
#pragma unroll
    for (int q = 0; q < 2; ++q) gl_lds16(srcA + (long)q * 8 * K, b0 + dA + q * 1024);
#pragma unroll
    for (int q = 0; q < 4; ++q) gl_lds16(srcB + (long)q * 8 * K, b0 + dB + q * 1024);
#pragma unroll
    for (int q = 0; q < 2; ++q) gl_lds16(srcA + (long)q * 8 * K + 64, b1 + dA + q * 1024);
#pragma unroll
    for (int q = 0; q < 4; ++q) gl_lds16(srcB + (long)q * 8 * K + 64, b1 + dB + q * 1024);
  }
  asm volatile("s_waitcnt vmcnt(6)" ::: "memory");
  __builtin_amdgcn_s_barrier();
  __builtin_amdgcn_sched_barrier(0);

  int ir = 0, is = 2;
  for (int t = 0; t < NT; ++t) {
    const char* bufR = lds + ir * SBUF;
    char* bufS = lds + is * SBUF;
    const int tst = (t + 2 < NT) ? t + 2 : NT - 1;
    const long kst = (long)tst * 64;

#pragma unroll
    for (int nf = 0; nf < 4; ++nf) bv[nf] = *(const bf16x8*)(bufR + boff + nf * 2048);
#pragma unroll
    for (int mf = 0; mf < 4; ++mf) af[mf] = *(const bf16x8*)(bufR + aoff + mf * 2048);
    gl_lds16(srcA + kst,                 bufS + dA);
    gl_lds16(srcA + (long)8 * K + kst,   bufS + dA + 1024);
    gl_lds16(srcB + kst,                 bufS + dB);
    __builtin_amdgcn_s_barrier();
    __builtin_amdgcn_s_setprio(1);
#pragma unroll
    for (int mf = 0; mf < 4; ++mf)
#pragma unroll
      for (int nf = 0; nf < 4; ++nf)
        acc[mf][nf] = __builtin_amdgcn_mfma_f32_16x16x32_bf16(af[mf], bv[nf], acc[mf][nf], 0, 0, 0);
    __builtin_amdgcn_s_setprio(0);
    __builtin_amdgcn_s_barrier();

#pragma unroll
    for (int nf = 0; nf < 4; ++nf) bv[nf] = *(const bf16x8*)(bufR + ((boff + nf * 2048) ^ 64));
#pragma unroll
    for (int mf = 0; mf < 4; ++mf) af[mf] = *(const bf16x8*)(bufR + ((aoff + mf * 2048) ^ 64));
    gl_lds16(srcB + (long)8 * K + kst,   bufS + dB + 1024);
    gl_lds16(srcB + (long)16 * K + kst,  bufS + dB + 2048);
    gl_lds16(srcB + (long)24 * K + kst,  bufS + dB + 3072);
    __builtin_amdgcn_s_barrier();
    __builtin_amdgcn_s_setprio(1);
#pragma unroll
    for (int mf = 0; mf < 4; ++mf)
#pragma unroll
      for (int nf = 0; nf < 4; ++nf)
        acc[mf][nf] = __builtin_amdgcn_mfma_f32_16x16x32_bf16(af[mf], bv[nf], acc[mf][nf], 0, 0, 0);
    __builtin_amdgcn_s_setprio(0);
    asm volatile("s_waitcnt vmcnt(6)" ::: "memory");
    __builtin_amdgcn_s_barrier();
    __builtin_amdgcn_sched_barrier(0);
    ir = (ir == 2) ? 0 : ir + 1;
    is = (is == 2) ? 0 : is + 1;
  }
  asm volatile("s_waitcnt vmcnt(0)" ::: "memory");

  const int colB0 = n0 + wn * 64 + (l & 15);
  const int rowB0 = m0 + wm * 64 + ((l >> 4) << 2);
#pragma unroll
  for (int mi = 0; mi < 4; ++mi) {
#pragma unroll
    for (int ni = 0; ni < 4; ++ni) {
      const int col = colB0 + ni * 16;
#pragma unroll
      for (int j = 0; j < 4; ++j) {
        const int row = rowB0 + mi * 16 + j;
        const float v = acc[mi][ni][j];
        if constexpr (EPI == EPI_BF16) {
          Cb[sCb * bz + (long)row * N + col] = (bf16_t)v;
        } else { // EPI_F32_BIAS_RES
          Cf[(long)row * N + col] = v + bias[col] + resid[(long)row * N + col];
        }
      }
    }
  }
}

// -- BM=128 x BN=256, BK=32, 3-buffer, counted vmcnt(3), 2 blocks/CU (QKV) --
__global__ __launch_bounds__(512, 2)
void gemm128_32(const bf16_t* __restrict__ A, const bf16_t* __restrict__ B,
                bf16_t* __restrict__ Cb, bf16_t* __restrict__ Cb2,
                bf16_t* __restrict__ Cb3,
                const float* __restrict__ bias, const float* __restrict__ bias2,
                const float* __restrict__ bias3, int M, int N, int K)
{
  constexpr int SBUF = 24576;
  __shared__ __align__(16) char lds[3 * SBUF];
  const int tid = threadIdx.x;
  const int l   = tid & 63;
  const int w   = tid >> 6;
  const int wm  = w >> 2, wn = w & 3;

  const int nx = gridDim.x, ny = gridDim.y;
  const int tot = nx * ny;
  int id = blockIdx.x + nx * blockIdx.y;
  const int cpx = tot >> 3;
  int sid = (id & 7) * cpx + (id >> 3);
  const int bx = sid % nx;
  const int by = sid / nx;

  const int m0 = by * 128, n0 = bx * 256;
  const int NT = K >> 5;

  const int srow = (l >> 2);
  const int scol = ((l & 3) ^ ((l >> 3) & 3)) * 8;
  const bf16_t* srcA = A + (long)(m0 + w * 16 + srow) * K + scol;
  const bf16_t* srcB0 = B + (long)(n0 + w * 32 + srow) * K + scol;
  const bf16_t* srcB1 = srcB0 + (long)16 * K;
  const int dA = w * 1024 + l * 16;
  const int dB = 8192 + w * 2048 + l * 16;

  const int rA = wm * 64 + (l & 15);
  const int rB = wn * 64 + (l & 15);
  const int xoff = 16 * ((l >> 4) ^ ((l >> 1) & 3));
  const int aoff = rA * 64 + xoff;
  const int boff = 8192 + rB * 64 + xoff;

  f32x4 acc[4][4] = {};
  bf16x8 af[4], bv[4];

  gl_lds16(srcA,       lds + dA);
  gl_lds16(srcB0,      lds + dB);
  gl_lds16(srcB1,      lds + dB + 1024);
  gl_lds16(srcA + 32,  lds + SBUF + dA);
  gl_lds16(srcB0 + 32, lds + SBUF + dB);
  gl_lds16(srcB1 + 32, lds + SBUF + dB + 1024);
  asm volatile("s_waitcnt vmcnt(3)" ::: "memory");
  __builtin_amdgcn_s_barrier();
  __builtin_amdgcn_sched_barrier(0);

  int ir = 0, is = 2;
  for (int t = 0; t < NT; ++t) {
    const char* bufR = lds + ir * SBUF;
    char* bufS = lds + is * SBUF;
    const long kst = (long)((t + 2 < NT) ? t + 2 : NT - 1) * 32;

#pragma unroll
    for (int nf = 0; nf < 4; ++nf) bv[nf] = *(const bf16x8*)(bufR + boff + nf * 1024);
#pragma unroll
    for (int mf = 0; mf < 4; ++mf) af[mf] = *(const bf16x8*)(bufR + aoff + mf * 1024);
    gl_lds16(srcA + kst, bufS + dA);
    gl_lds16(srcB0 + kst, bufS + dB);
    gl_lds16(srcB1 + kst, bufS + dB + 1024);
    __builtin_amdgcn_s_setprio(1);
#pragma unroll
    for (int mf = 0; mf < 4; ++mf)
#pragma unroll
      for (int nf = 0; nf < 4; ++nf)
        acc[mf][nf] = __builtin_amdgcn_mfma_f32_16x16x32_bf16(af[mf], bv[nf], acc[mf][nf], 0, 0, 0);
    __builtin_amdgcn_s_setprio(0);
    asm volatile("s_waitcnt vmcnt(3)" ::: "memory");
    __builtin_amdgcn_s_barrier();
    __builtin_amdgcn_sched_barrier(0);
    ir = (ir == 2) ? 0 : ir + 1;
    is = (is == 2) ? 0 : is + 1;
  }
  asm volatile("s_waitcnt vmcnt(0)" ::: "memory");

  const int colB0 = n0 + wn * 64 + (l & 15);
  const int rowB0 = m0 + wm * 64 + ((l >> 4) << 2);
#pragma unroll
  for (int mi = 0; mi < 4; ++mi) {
#pragma unroll
    for (int ni = 0; ni < 4; ++ni) {
      const int col = colB0 + ni * 16;
#pragma unroll
      for (int j = 0; j < 4; ++j) {
        const int row = rowB0 + mi * 16 + j;
        const float v = acc[mi][ni][j];
        if (col < 1024)      Cb [(long)row * 1024 + col]        = (bf16_t)(v + bias[col]);
        else if (col < 2048) Cb2[(long)row * 1024 + col - 1024] = (bf16_t)(v + bias2[col - 1024]);
        else                 Cb3[(long)row * 1024 + col - 2048] = (bf16_t)(v + bias3[col - 2048]);
      }
    }
  }
}

// bf16 transpose: V [4][2048][1024] -> VT [4][1024][2048]. 64x64 tiles.
__global__ __launch_bounds__(256)
void transpose_bf(const bf16_t* __restrict__ V, bf16_t* __restrict__ VT)
{
  __shared__ __align__(16) bf16_t t[64][72];
  const int b = blockIdx.z;
  const int t0 = blockIdx.y * 64, d0 = blockIdx.x * 64;
  const int r = threadIdx.x >> 3;
  const int c = (threadIdx.x & 7) * 8;
  const bf16_t* src = V + ((long)b * 2048 + t0) * 1024 + d0;
#pragma unroll
  for (int h = 0; h < 2; ++h)
    *(bf16x8*)&t[r + 32 * h][c] = *(const bf16x8*)(src + (long)(r + 32 * h) * 1024 + c);
  __syncthreads();
  bf16_t* dst = VT + ((long)b * 1024 + d0) * 2048 + t0;
#pragma unroll
  for (int h = 0; h < 2; ++h) {
    const int d = r + 32 * h;
    bf16x8 o;
#pragma unroll
    for (int j = 0; j < 8; ++j) o[j] = t[c + j][d];
    *(bf16x8*)(dst + (long)d * 2048 + c) = o;
  }
}

// All 6 weight transposes in one dispatch. Flat grid 12288 blocks.
__global__ __launch_bounds__(256)
void transpose_all(const float* __restrict__ Wq, const float* __restrict__ Wk,
                   const float* __restrict__ Wv, const float* __restrict__ Wo,
                   const float* __restrict__ W1, const float* __restrict__ W2,
                   bf16_t* __restrict__ WqkvT, bf16_t* __restrict__ WoT,
                   bf16_t* __restrict__ W1T, bf16_t* __restrict__ W2T)
{
  const int id = blockIdx.x;
  const float* W; bf16_t* WT; int R, C, cb, rb;
  if (id < 4096) {
    const int wsel = id >> 10, loc = id & 1023;
    cb = loc & 31; rb = loc >> 5; R = 1024; C = 1024;
    if (wsel == 0)      { W = Wq; WT = WqkvT; }
    else if (wsel == 1) { W = Wk; WT = WqkvT + 1024L * 1024; }
    else if (wsel == 2) { W = Wv; WT = WqkvT + 2048L * 1024; }
    else                { W = Wo; WT = WoT; }
  } else if (id < 8192) {
    const int loc = id - 4096;
    cb = loc & 127; rb = loc >> 7; R = 1024; C = 4096;
    W = W1; WT = W1T;
  } else {
    const int loc = id - 8192;
    cb = loc & 31; rb = loc >> 5; R = 4096; C = 1024;
    W = W2; WT = W2T;
  }
  __shared__ float t[32][33];
  const int c0 = cb * 32, r0 = rb * 32;
  const int tx = threadIdx.x & 31, ty = threadIdx.x >> 5;
#pragma unroll
  for (int i = 0; i < 32; i += 8)
    t[ty + i][tx] = W[(long)(r0 + ty + i) * C + c0 + tx];
  __syncthreads();
#pragma unroll
  for (int i = 0; i < 32; i += 8)
    WT[(long)(c0 + ty + i) * R + r0 + tx] = (bf16_t)t[tx][ty + i];
}

// LayerNorm over D=1024, one block (256 thr) per row, out = bf16.
__global__ __launch_bounds__(256)
void ln_kernel(const float* __restrict__ x, const float* __restrict__ g,
               const float* __restrict__ be, bf16_t* __restrict__ out)
{
  const long row = blockIdx.x;
  const float4 v = *(const float4*)(x + row * 1024 + threadIdx.x * 4);
  float s  = v.x + v.y + v.z + v.w;
  float s2 = v.x * v.x + v.y * v.y + v.z * v.z + v.w * v.w;
  __shared__ float red[10];
  const int lane = threadIdx.x & 63, w = threadIdx.x >> 6;
#pragma unroll
  for (int off = 32; off; off >>= 1) {
    s  += __shfl_down(s, off);
    s2 += __shfl_down(s2, off);
  }
  if (lane == 0) { red[w] = s; red[4 + w] = s2; }
  __syncthreads();
  if (threadIdx.x == 0) {
    const float ts = red[0] + red[1] + red[2] + red[3];
    const float t2 = red[4] + red[5] + red[6] + red[7];
    const float mu = ts * (1.f / 1024.f);
    const float var = t2 * (1.f / 1024.f) - mu * mu;
    red[8] = mu;
    red[9] = rsqrtf(var + 1e-5f);
  }
  __syncthreads();
  const float mu = red[8], rinv = red[9];
  const int c = threadIdx.x * 4;
  const float4 gv = *(const float4*)(g + c);
  const float4 bvv = *(const float4*)(be + c);
  bf16_t* o = out + row * 1024 + c;
  o[0] = (bf16_t)((v.x - mu) * rinv * gv.x + bvv.x);
  o[1] = (bf16_t)((v.y - mu) * rinv * gv.y + bvv.y);
  o[2] = (bf16_t)((v.z - mu) * rinv * gv.z + bvv.z);
  o[3] = (bf16_t)((v.w - mu) * rinv * gv.w + bvv.w);
}

// Row softmax over S=2048: reads bf16 S from ab, writes fp32 attn to sc and
// bf16 P in-place to ab. One block (256 thr) per row.
__global__ __launch_bounds__(256)
void softmax_kernel(float* __restrict__ sc, bf16_t* __restrict__ ab)
{
  const long row = blockIdx.x;
  const int t0 = threadIdx.x * 8;
  const bf16x8 v8 = *(const bf16x8*)(ab + row * 2048 + t0);
  float e[8];
#pragma unroll
  for (int j = 0; j < 8; ++j) e[j] = (float)v8[j];
  float mx = fmaxf(fmaxf(fmaxf(e[0], e[1]), fmaxf(e[2], e[3])),
                   fmaxf(fmaxf(e[4], e[5]), fmaxf(e[6], e[7])));
  __shared__ float red[4];
  __shared__ float bc[2];
  const int lane = threadIdx.x & 63, w = threadIdx.x >> 6;
#pragma unroll
  for (int off = 32; off; off >>= 1) mx = fmaxf(mx, __shfl_down(mx, off));
  if (lane == 0) red[w] = mx;
  __syncthreads();
  if (threadIdx.x == 0) bc[0] = fmaxf(fmaxf(red[0], red[1]), fmaxf(red[2], red[3]));
  __syncthreads();
  const float m = bc[0];
  float s = 0.f;
#pragma unroll
  for (int j = 0; j < 8; ++j) { e[j] = __expf(e[j] - m); s += e[j]; }
#pragma unroll
  for (int off = 32; off; off >>= 1) s += __shfl_down(s, off);
  __syncthreads();
  if (lane == 0) red[w] = s;
  __syncthreads();
  if (threadIdx.x == 0) bc[1] = 1.f / (red[0] + red[1] + red[2] + red[3]);
  __syncthreads();
  const float inv = bc[1];
  float4 oa, ob;
  oa.x = e[0] * inv; oa.y = e[1] * inv; oa.z = e[2] * inv; oa.w = e[3] * inv;
  ob.x = e[4] * inv; ob.y = e[5] * inv; ob.z = e[6] * inv; ob.w = e[7] * inv;
  *(float4*)(sc + row * 2048 + t0)     = oa;
  *(float4*)(sc + row * 2048 + t0 + 4) = ob;
  bf16x8 o8;
  o8[0] = (bf16_t)oa.x; o8[1] = (bf16_t)oa.y; o8[2] = (bf16_t)oa.z; o8[3] = (bf16_t)oa.w;
  o8[4] = (bf16_t)ob.x; o8[5] = (bf16_t)ob.y; o8[6] = (bf16_t)ob.z; o8[7] = (bf16_t)ob.w;
  *(bf16x8*)(ab + row * 2048 + t0) = o8;
}

extern "C" void kernel_launch(void* const* d_in, const int* in_sizes, int n_in,
                              void* d_out, int out_size, void* d_ws, size_t ws_size,
                              hipStream_t stream)
{
  const float* x   = (const float*)d_in[0];
  const float* Wq  = (const float*)d_in[1];
  const float* bq  = (const float*)d_in[2];
  const float* Wk  = (const float*)d_in[3];
  const float* bk  = (const float*)d_in[4];
  const float* Wv  = (const float*)d_in[5];
  const float* bv  = (const float*)d_in[6];
  const float* Wo  = (const float*)d_in[7];
  const float* bo  = (const float*)d_in[8];
  const float* g1  = (const float*)d_in[9];
  const float* be1 = (const float*)d_in[10];
  const float* g2  = (const float*)d_in[11];
  const float* be2 = (const float*)d_in[12];
  const float* W1  = (const float*)d_in[13];
  const float* b1  = (const float*)d_in[14];
  const float* W2  = (const float*)d_in[15];
  const float* b2  = (const float*)d_in[16];

  float* out   = (float*)d_out;
  float* attnF = out + 8192L * 1024;        // [4][2048][2048] fp32 (softmax out)
  bf16_t* vB   = (bf16_t*)attnF;            // scratch: row-major v (pre-scores)

  char* ws = (char*)d_ws;
  const size_t MB = 1024 * 1024;
  bf16_t* WqkvT = (bf16_t*)(ws + 0 * MB);   // [3072][1024]
  bf16_t* WoT   = (bf16_t*)(ws + 6 * MB);
  bf16_t* W1T   = (bf16_t*)(ws + 8 * MB);
  bf16_t* W2T   = (bf16_t*)(ws + 16 * MB);
  bf16_t* xn    = (bf16_t*)(ws + 24 * MB);
  bf16_t* qB    = (bf16_t*)(ws + 40 * MB);  // q, later attn_out
  bf16_t* kB    = (bf16_t*)(ws + 56 * MB);
  bf16_t* vT    = (bf16_t*)(ws + 72 * MB);  // [4][1024][2048]
  bf16_t* atB   = (bf16_t*)(ws + 88 * MB);  // S bf16, then P bf16
  float*  x2    = (float* )(ws + 120 * MB);
  bf16_t* hB    = (bf16_t*)(ws + 56 * MB);  // FFN hidden, reuses kB/vT/atB

  transpose_all<<<12288, 256, 0, stream>>>(
      Wq, Wk, Wv, Wo, W1, W2, WqkvT, WoT, W1T, W2T);

  ln_kernel<<<8192, 256, 0, stream>>>(x, g1, be1, xn);

  // fused QKV: 768 blocks, 2 blocks/CU, 3-buffer counted-vmcnt pipeline
  gemm128_32<<<dim3(12, 64), 512, 0, stream>>>(
      xn, WqkvT, qB, kB, vB, bq, bk, bv, 8192, 3072, 1024);

  // v -> vT; must finish before softmax overwrites vB region
  transpose_bf<<<dim3(16, 32, 4), 256, 0, stream>>>(vB, vT);

  // scores = q k^T / sqrt(D) -> atB (bf16)
  gemm8p<256, EPI_BF16_SCALE><<<dim3(8, 8, 4), 512, 0, stream>>>(
      qB, kB, nullptr, atB, nullptr,
      2048, 2048, 1024, 2048L * 1024, 2048L * 1024, 2048L * 2048, 0.03125f);

  // softmax: reads bf16 S, writes fp32 attn to d_out + bf16 P in-place
  softmax_kernel<<<8192, 256, 0, stream>>>(attnF, atB);

  // attn_out = P @ v -> ao (reuse qB)
  gemm128<EPI_BF16><<<dim3(4, 16, 4), 512, 0, stream>>>(
      atB, vT, nullptr, qB, nullptr, nullptr,
      2048, 1024, 2048, 2048L * 2048, 1024L * 2048, 2048L * 1024);

  // x2 = x + ao @ Wo + bo
  gemm128<EPI_F32_BIAS_RES><<<dim3(4, 64, 1), 512, 0, stream>>>(
      qB, WoT, x2, nullptr, bo, x,
      8192, 1024, 1024, 0, 0, 0);

  ln_kernel<<<8192, 256, 0, stream>>>(x2, g2, be2, xn);

  gemm8p<256, EPI_BF16_RELU_BIAS><<<dim3(16, 32, 1), 512, 0, stream>>>(
      xn, W1T, nullptr, hB, b1,
      8192, 4096, 1024, 0, 0, 0, 1.f);
  gemm128<EPI_F32_BIAS_RES><<<dim3(4, 64, 1), 512, 0, stream>>>(
      hB, W2T, out, nullptr, b2, x2,
      8192, 1024, 4096, 0, 0, 0);
}